// Round 4
// baseline (540.798 us; speedup 1.0000x reference)
//
#include <hip/hip_runtime.h>
#include <hip/hip_bf16.h>

#define EMBED 1024
#define THREE_EMBED 3072
#define NHEAD 16
#define HDIM 64
#define MTOT 16384
#define LTOT 16383

typedef __attribute__((ext_vector_type(8))) short bf16x8;
typedef __attribute__((ext_vector_type(4))) float f32x4;

__device__ __forceinline__ unsigned short f2b(float f) {
  union { float f; unsigned u; } v; v.f = f;
  unsigned r = v.u + 0x7fffu + ((v.u >> 16) & 1u);
  return (unsigned short)(r >> 16);
}
__device__ __forceinline__ float b2f(unsigned short h) {
  union { unsigned u; float f; } v; v.u = ((unsigned)h) << 16;
  return v.f;
}

__device__ __forceinline__ void gload16(const void* g, void* l) {
  __builtin_amdgcn_global_load_lds(
      (const __attribute__((address_space(1))) void*)g,
      (__attribute__((address_space(3))) void*)l, 16, 0, 0);
}

// ---------------------------------------------------------------------------
// cast pass: x (+padding) -> xb bf16; qkv_w -> wqb bf16; inv[kvi[i]] = i
// ---------------------------------------------------------------------------
__global__ __launch_bounds__(256) void cast_inputs(
    const float* __restrict__ x, const float* __restrict__ padding,
    const float* __restrict__ wq, const int* __restrict__ kvi,
    unsigned short* __restrict__ xb, unsigned short* __restrict__ wqb,
    int* __restrict__ inv)
{
  const int NX = MTOT * EMBED / 8;
  const int NQ = THREE_EMBED * EMBED / 8;
  const int total = NX + NQ;
  int g = blockIdx.x * 256 + threadIdx.x;
  const int stride = gridDim.x * 256;
  for (; g < total + MTOT; g += stride) {
    if (g >= total) {
      int i = g - total;
      inv[kvi[i]] = i;
      continue;
    }
    const float* src;
    unsigned short* dst;
    if (g < NX) {
      size_t e = (size_t)g * 8;
      int row = (int)(e >> 10);
      src = (row < LTOT) ? (x + e) : (padding + (e - (size_t)LTOT * 1024));
      dst = xb + e;
    } else {
      size_t e = (size_t)(g - NX) * 8;
      src = wq + e;
      dst = wqb + e;
    }
    float4 a = *(const float4*)src;
    float4 b = *(const float4*)(src + 4);
    ushort4 u0, u1;
    u0.x = f2b(a.x); u0.y = f2b(a.y); u0.z = f2b(a.z); u0.w = f2b(a.w);
    u1.x = f2b(b.x); u1.y = f2b(b.y); u1.z = f2b(b.z); u1.w = f2b(b.w);
    *(ushort4*)dst = u0;
    *(ushort4*)(dst + 4) = u1;
  }
}

// ---------------------------------------------------------------------------
// GEMM1 (m97): qkv = xb @ wqb^T + qkv_b. Epilogue applies bias + RoPE
// (+0.125 scale on Q) and scatters to head-major, window-permuted layout:
// qkvh[(part*16+h)][i = inv[row]][d].  RoPE partner d^32 is ni^2 (same lane).
// ---------------------------------------------------------------------------
__global__ __launch_bounds__(256) void gemm_qkv(
    const unsigned short* __restrict__ A, const unsigned short* __restrict__ B,
    const float* __restrict__ bias, const int* __restrict__ inv,
    const float* __restrict__ rope_cos, const float* __restrict__ rope_sin,
    unsigned short* __restrict__ qkvh)
{
  __shared__ __align__(16) unsigned short sA[128 * 32];
  __shared__ __align__(16) unsigned short sB[128 * 32];
  const int t = threadIdx.x;
  const int lane = t & 63, wid = t >> 6;
  const int l15 = lane & 15, quad = lane >> 4;
  const int wm = (wid >> 1) * 64, wn = (wid & 1) * 64;
  const int bm = blockIdx.x, bn = blockIdx.y;

  const int r0 = t >> 2, c8 = (t & 3) * 8;
  const unsigned short* gA0 = A + (size_t)(bm * 128 + r0) * EMBED + c8;
  const unsigned short* gB0 = B + (size_t)(bn * 128 + r0) * EMBED + c8;
  unsigned short* lA0 = sA + wid * 512;
  unsigned short* lA1 = sA + 2048 + wid * 512;
  unsigned short* lB0 = sB + wid * 512;
  unsigned short* lB1 = sB + 2048 + wid * 512;

  f32x4 acc[4][4];
#pragma unroll
  for (int i = 0; i < 4; ++i)
#pragma unroll
    for (int j = 0; j < 4; ++j) acc[i][j] = (f32x4){0.f, 0.f, 0.f, 0.f};

  for (int k0 = 0; k0 < EMBED; k0 += 32) {
    __syncthreads();
    gload16(gA0 + k0, lA0);
    gload16(gA0 + 64 * EMBED + k0, lA1);
    gload16(gB0 + k0, lB0);
    gload16(gB0 + 64 * EMBED + k0, lB1);
    __syncthreads();
    bf16x8 af[4], bfr[4];
#pragma unroll
    for (int mi = 0; mi < 4; ++mi)
      af[mi] = *(const bf16x8*)(sA + (wm + mi * 16 + l15) * 32 + quad * 8);
#pragma unroll
    for (int ni = 0; ni < 4; ++ni)
      bfr[ni] = *(const bf16x8*)(sB + (wn + ni * 16 + l15) * 32 + quad * 8);
#pragma unroll
    for (int mi = 0; mi < 4; ++mi)
#pragma unroll
      for (int ni = 0; ni < 4; ++ni)
        acc[mi][ni] = __builtin_amdgcn_mfma_f32_16x16x32_bf16(
            af[mi], bfr[ni], acc[mi][ni], 0, 0, 0);
  }

  // Epilogue: bias + (RoPE | scale) + head-major permuted scatter.
  const int hh = (bn * 128 + wn) >> 6;   // 0..47 enumerates (part, head)
  const int part = hh >> 4;              // 0=Q 1=K 2=V (wave-uniform)
  unsigned short* buf = qkvh + (size_t)hh * (MTOT * HDIM);
  float bv[4];
#pragma unroll
  for (int ni = 0; ni < 4; ++ni) bv[ni] = bias[bn * 128 + wn + ni * 16 + l15];
#pragma unroll
  for (int mi = 0; mi < 4; ++mi) {
#pragma unroll
    for (int reg = 0; reg < 4; ++reg) {
      int row = bm * 128 + wm + mi * 16 + quad * 4 + reg;
      int i = inv[row];
      float a[4];
#pragma unroll
      for (int ni = 0; ni < 4; ++ni) a[ni] = acc[mi][ni][reg] + bv[ni];
      if (part < 2) {
        const float* cp = rope_cos + (size_t)i * HDIM;
        const float* sp = rope_sin + (size_t)i * HDIM;
        float o[4];
#pragma unroll
        for (int ni = 0; ni < 4; ++ni) {
          int d = ni * 16 + l15;
          float c = cp[d], s = sp[d];
          float rot = (ni < 2) ? -a[ni ^ 2] : a[ni ^ 2];
          o[ni] = a[ni] * c + rot * s;
        }
        float sc = (part == 0) ? 0.125f : 1.0f;
#pragma unroll
        for (int ni = 0; ni < 4; ++ni) a[ni] = o[ni] * sc;
      }
#pragma unroll
      for (int ni = 0; ni < 4; ++ni) {
        buf[(size_t)i * HDIM + ni * 16 + l15] = f2b(a[ni]);
      }
    }
  }
}

// ---------------------------------------------------------------------------
// Attention: one block per (window, head). Q/K/V pre-gathered, pre-RoPE'd,
// head-major -> staging is a pure copy. Output scattered via kvi.
// ---------------------------------------------------------------------------
__global__ __launch_bounds__(256, 4) void attn(
    const unsigned short* __restrict__ qkvh,
    const int* __restrict__ kvi,
    unsigned short* __restrict__ ori)
{
  __shared__ __align__(16) unsigned short sK[128 * 64];   // [key][d] swizzled
  __shared__ __align__(16) unsigned short sV[64 * 128];   // [d][key] swizzled
  __shared__ __align__(16) unsigned short sP[4][16 * 40]; // per-wave P chunk

  const int t = threadIdx.x;
  const int lane = t & 63, wid = t >> 6;
  const int l15 = lane & 15, quad = lane >> 4;
  const int wwin = blockIdx.x >> 4;
  const int h = blockIdx.x & 15;

  const unsigned short* Qh = qkvh + (size_t)h * (MTOT * HDIM);
  const unsigned short* Kh = qkvh + (size_t)(16 + h) * (MTOT * HDIM);
  const unsigned short* Vh = qkvh + (size_t)(32 + h) * (MTOT * HDIM);

  f32x4 accO[4][4];
  float mrow[4][4], lrow[4][4];
#pragma unroll
  for (int qt = 0; qt < 4; ++qt) {
#pragma unroll
    for (int nt = 0; nt < 4; ++nt) accO[qt][nt] = (f32x4){0.f, 0.f, 0.f, 0.f};
#pragma unroll
    for (int reg = 0; reg < 4; ++reg) { mrow[qt][reg] = -1e30f; lrow[qt][reg] = 0.f; }
  }

  // Q fragments: straight loads (RoPE + scale already applied).
  bf16x8 qa[4][2];
#pragma unroll
  for (int qt = 0; qt < 4; ++qt) {
    int i = wwin * 256 + wid * 64 + qt * 16 + l15;
    const unsigned short* qp = Qh + (size_t)i * HDIM;
    qa[qt][0] = *(const bf16x8*)(qp + quad * 8);
    qa[qt][1] = *(const bf16x8*)(qp + 32 + quad * 8);
  }

  for (int half = 0; half < 2; ++half) {
    __syncthreads();
    {
      int key = t >> 1, hx = t & 1;  // each thread: 32 d-values of one key
      int i = wwin * 256 + half * 128 + key;
      const unsigned short* kp = Kh + (size_t)i * HDIM + hx * 32;
      // K: 4 chunks of 8 elems, swizzled by key&7 — pure copy
#pragma unroll
      for (int cc = 0; cc < 4; ++cc) {
        int c = hx * 4 + cc;
        uint4 kv = *(const uint4*)(kp + cc * 8);
        *(uint4*)(sK + key * 64 + ((c ^ (key & 7)) * 8)) = kv;
      }
      // V: transpose to [d][key], swizzled by d&7
      const unsigned short* vp = Vh + (size_t)i * HDIM + hx * 32;
      int kc3 = key >> 3, k7 = key & 7;
#pragma unroll
      for (int c = 0; c < 4; ++c) {
        bf16x8 va = *(const bf16x8*)(vp + c * 8);
#pragma unroll
        for (int j = 0; j < 8; ++j) {
          int d = hx * 32 + c * 8 + j;
          sV[d * 128 + ((kc3 ^ (d & 7)) * 8) + k7] = (unsigned short)va[j];
        }
      }
    }
    __syncthreads();

#pragma unroll
    for (int qt = 0; qt < 4; ++qt) {
      f32x4 accS[8];
#pragma unroll
      for (int nt = 0; nt < 8; ++nt) accS[nt] = (f32x4){0.f, 0.f, 0.f, 0.f};
#pragma unroll
      for (int ks = 0; ks < 2; ++ks) {
#pragma unroll
        for (int nt = 0; nt < 8; ++nt) {
          int key = nt * 16 + l15;
          bf16x8 bk = *(const bf16x8*)(
              sK + key * 64 + (((ks * 4 + quad) ^ (key & 7)) * 8));
          accS[nt] = __builtin_amdgcn_mfma_f32_16x16x32_bf16(
              qa[qt][ks], bk, accS[nt], 0, 0, 0);
        }
      }
#pragma unroll
      for (int reg = 0; reg < 4; ++reg) {
        float mx = accS[0][reg];
#pragma unroll
        for (int nt = 1; nt < 8; ++nt) mx = fmaxf(mx, accS[nt][reg]);
#pragma unroll
        for (int off = 1; off < 16; off <<= 1)
          mx = fmaxf(mx, __shfl_xor(mx, off, 64));
        float mold = mrow[qt][reg];
        float mnew = fmaxf(mold, mx);
        float alpha = __expf(mold - mnew);
        mrow[qt][reg] = mnew;
        float ls = 0.f;
#pragma unroll
        for (int nt = 0; nt < 8; ++nt) {
          float p = __expf(accS[nt][reg] - mnew);
          accS[nt][reg] = p;
          ls += p;
        }
#pragma unroll
        for (int off = 1; off < 16; off <<= 1) ls += __shfl_xor(ls, off, 64);
        lrow[qt][reg] = lrow[qt][reg] * alpha + ls;
#pragma unroll
        for (int nt = 0; nt < 4; ++nt) accO[qt][nt][reg] *= alpha;
      }
#pragma unroll
      for (int kc = 0; kc < 4; ++kc) {
#pragma unroll
        for (int nt2 = 0; nt2 < 2; ++nt2) {
#pragma unroll
          for (int reg = 0; reg < 4; ++reg) {
            sP[wid][(quad * 4 + reg) * 40 + nt2 * 16 + l15] =
                f2b(accS[kc * 2 + nt2][reg]);
          }
        }
        bf16x8 pa = *(const bf16x8*)(&sP[wid][l15 * 40 + quad * 8]);
#pragma unroll
        for (int nt = 0; nt < 4; ++nt) {
          int d = nt * 16 + l15;
          bf16x8 bv = *(const bf16x8*)(
              sV + d * 128 + (((kc * 4 + quad) ^ (d & 7)) * 8));
          accO[qt][nt] = __builtin_amdgcn_mfma_f32_16x16x32_bf16(
              pa, bv, accO[qt][nt], 0, 0, 0);
        }
      }
    }
  }

#pragma unroll
  for (int qt = 0; qt < 4; ++qt) {
#pragma unroll
    for (int reg = 0; reg < 4; ++reg) {
      int i = wwin * 256 + wid * 64 + qt * 16 + quad * 4 + reg;
      int orow = kvi[i];
      float inv = 1.0f / lrow[qt][reg];
      unsigned short* op = ori + (size_t)orow * EMBED + h * HDIM;
#pragma unroll
      for (int nt = 0; nt < 4; ++nt) {
        op[nt * 16 + l15] = f2b(accO[qt][nt][reg] * inv);
      }
    }
  }
}

// ---------------------------------------------------------------------------
// GEMM2: out = ori[:L] @ proj_w^T + proj_b. A bf16 via global_load_lds;
// B fp32 inline-converted; out fp32.
// ---------------------------------------------------------------------------
__global__ __launch_bounds__(256) void gemm_proj(
    const unsigned short* __restrict__ A, const float* __restrict__ w,
    const float* __restrict__ bias, float* __restrict__ out)
{
  __shared__ __align__(16) unsigned short sA[128 * 32];
  __shared__ __align__(16) unsigned short sB[128 * 32];
  const int t = threadIdx.x;
  const int lane = t & 63, wid = t >> 6;
  const int l15 = lane & 15, quad = lane >> 4;
  const int wm = (wid >> 1) * 64, wn = (wid & 1) * 64;
  const int bm = blockIdx.x, bn = blockIdx.y;

  const int r0 = t >> 2, c8 = (t & 3) * 8;
  const unsigned short* gA0 = A + (size_t)(bm * 128 + r0) * EMBED + c8;
  unsigned short* lA0 = sA + wid * 512;
  unsigned short* lA1 = sA + 2048 + wid * 512;
  const int rb = t >> 3, cb = t & 7;

  f32x4 acc[4][4];
#pragma unroll
  for (int i = 0; i < 4; ++i)
#pragma unroll
    for (int j = 0; j < 4; ++j) acc[i][j] = (f32x4){0.f, 0.f, 0.f, 0.f};

  for (int k0 = 0; k0 < EMBED; k0 += 32) {
    __syncthreads();
    gload16(gA0 + k0, lA0);
    gload16(gA0 + 64 * EMBED + k0, lA1);
#pragma unroll
    for (int ri = 0; ri < 4; ++ri) {
      int r = rb + 32 * ri;
      float4 v = *(const float4*)(w + (size_t)(bn * 128 + r) * EMBED + k0 + cb * 4);
      ushort4 b;
      b.x = f2b(v.x); b.y = f2b(v.y); b.z = f2b(v.z); b.w = f2b(v.w);
      *(ushort4*)(sB + r * 32 + cb * 4) = b;
    }
    __syncthreads();
    bf16x8 af[4], bfr[4];
#pragma unroll
    for (int mi = 0; mi < 4; ++mi)
      af[mi] = *(const bf16x8*)(sA + (wm + mi * 16 + l15) * 32 + quad * 8);
#pragma unroll
    for (int ni = 0; ni < 4; ++ni)
      bfr[ni] = *(const bf16x8*)(sB + (wn + ni * 16 + l15) * 32 + quad * 8);
#pragma unroll
    for (int mi = 0; mi < 4; ++mi)
#pragma unroll
      for (int ni = 0; ni < 4; ++ni)
        acc[mi][ni] = __builtin_amdgcn_mfma_f32_16x16x32_bf16(
            af[mi], bfr[ni], acc[mi][ni], 0, 0, 0);
  }

#pragma unroll
  for (int ni = 0; ni < 4; ++ni) {
    int col = bn * 128 + wn + ni * 16 + l15;
    float bv = bias[col];
#pragma unroll
    for (int mi = 0; mi < 4; ++mi) {
#pragma unroll
      for (int reg = 0; reg < 4; ++reg) {
        int row = bm * 128 + wm + mi * 16 + quad * 4 + reg;
        if (row < LTOT) out[(size_t)row * EMBED + col] = acc[mi][ni][reg] + bv;
      }
    }
  }
}

// ---------------------------------------------------------------------------
extern "C" void kernel_launch(void* const* d_in, const int* in_sizes, int n_in,
                              void* d_out, int out_size, void* d_ws, size_t ws_size,
                              hipStream_t stream) {
  const float* x        = (const float*)d_in[0];
  const float* qkv_w    = (const float*)d_in[1];
  const float* qkv_b    = (const float*)d_in[2];
  const float* proj_w   = (const float*)d_in[3];
  const float* proj_b   = (const float*)d_in[4];
  const float* padding  = (const float*)d_in[5];
  const float* rope_cos = (const float*)d_in[6];
  const float* rope_sin = (const float*)d_in[7];
  const int*   kvi      = (const int*)d_in[8];

  // ws layout (134.2 MB, proven safe):
  //   [0, 100.66M):       qkvh — head-major, window-permuted, RoPE'd
  //                       [48][16384][64] bf16
  //   [100.66M, +33.55M): xb (cast+gemm_qkv) then ori (attn+gemm_proj)
  // d_out scratch (dead before gemm_proj's full overwrite):
  //   head: wqb (6.3 MB);  tail: inv (64 KB int32)
  unsigned short* qkvh = (unsigned short*)d_ws;
  unsigned short* R    = (unsigned short*)((char*)d_ws +
                            (size_t)MTOT * THREE_EMBED * 2);
  unsigned short* xb  = R;
  unsigned short* ori = R;
  unsigned short* wqb = (unsigned short*)d_out;
  int* inv = (int*)((char*)d_out + (size_t)LTOT * EMBED * 4 - (size_t)MTOT * 4);
  float* out = (float*)d_out;

  cast_inputs<<<4096, 256, 0, stream>>>(x, padding, qkv_w, kvi, xb, wqb, inv);
  gemm_qkv<<<dim3(128, 24), 256, 0, stream>>>(xb, wqb, qkv_b, inv,
                                              rope_cos, rope_sin, qkvh);
  attn<<<dim3(64 * 16), 256, 0, stream>>>(qkvh, kvi, ori);
  gemm_proj<<<dim3(128, 8), 256, 0, stream>>>(ori, proj_w, proj_b, out);
}

// Round 5
// 470.918 us; speedup vs baseline: 1.1484x; 1.1484x over previous
//
#include <hip/hip_runtime.h>
#include <hip/hip_bf16.h>

#define EMBED 1024
#define THREE_EMBED 3072
#define NHEAD 16
#define HDIM 64
#define MTOT 16384
#define LTOT 16383

typedef __attribute__((ext_vector_type(8))) short bf16x8;
typedef __attribute__((ext_vector_type(4))) float f32x4;

__device__ __forceinline__ unsigned short f2b(float f) {
  union { float f; unsigned u; } v; v.f = f;
  unsigned r = v.u + 0x7fffu + ((v.u >> 16) & 1u);
  return (unsigned short)(r >> 16);
}
__device__ __forceinline__ float b2f(unsigned short h) {
  union { unsigned u; float f; } v; v.u = ((unsigned)h) << 16;
  return v.f;
}

__device__ __forceinline__ void gload16(const void* g, void* l) {
  __builtin_amdgcn_global_load_lds(
      (const __attribute__((address_space(1))) void*)g,
      (__attribute__((address_space(3))) void*)l, 16, 0, 0);
}

// ---------------------------------------------------------------------------
// cast pass: x (+padding) -> xb bf16; qkv_w -> wqb bf16; inv[kvi[i]] = i
// ---------------------------------------------------------------------------
__global__ __launch_bounds__(256) void cast_inputs(
    const float* __restrict__ x, const float* __restrict__ padding,
    const float* __restrict__ wq, const int* __restrict__ kvi,
    unsigned short* __restrict__ xb, unsigned short* __restrict__ wqb,
    int* __restrict__ inv)
{
  const int NX = MTOT * EMBED / 8;
  const int NQ = THREE_EMBED * EMBED / 8;
  const int total = NX + NQ;
  int g = blockIdx.x * 256 + threadIdx.x;
  const int stride = gridDim.x * 256;
  for (; g < total + MTOT; g += stride) {
    if (g >= total) {
      int i = g - total;
      inv[kvi[i]] = i;
      continue;
    }
    const float* src;
    unsigned short* dst;
    if (g < NX) {
      size_t e = (size_t)g * 8;
      int row = (int)(e >> 10);
      src = (row < LTOT) ? (x + e) : (padding + (e - (size_t)LTOT * 1024));
      dst = xb + e;
    } else {
      size_t e = (size_t)(g - NX) * 8;
      src = wq + e;
      dst = wqb + e;
    }
    float4 a = *(const float4*)src;
    float4 b = *(const float4*)(src + 4);
    ushort4 u0, u1;
    u0.x = f2b(a.x); u0.y = f2b(a.y); u0.z = f2b(a.z); u0.w = f2b(a.w);
    u1.x = f2b(b.x); u1.y = f2b(b.y); u1.z = f2b(b.z); u1.w = f2b(b.w);
    *(ushort4*)dst = u0;
    *(ushort4*)(dst + 4) = u1;
  }
}

// ---------------------------------------------------------------------------
// GEMM1 (m97): qkv = xb @ wqb^T + qkv_b. Epilogue: bias + scatter to
// head-major window-permuted layout qkvh[(part*16+h)][i=inv[row]][d].
// (RoPE deliberately NOT here — it cost ~128 uncoalesced VMEM/thread in R4.)
// ---------------------------------------------------------------------------
__global__ __launch_bounds__(256) void gemm_qkv(
    const unsigned short* __restrict__ A, const unsigned short* __restrict__ B,
    const float* __restrict__ bias, const int* __restrict__ inv,
    unsigned short* __restrict__ qkvh)
{
  __shared__ __align__(16) unsigned short sA[128 * 32];
  __shared__ __align__(16) unsigned short sB[128 * 32];
  const int t = threadIdx.x;
  const int lane = t & 63, wid = t >> 6;
  const int l15 = lane & 15, quad = lane >> 4;
  const int wm = (wid >> 1) * 64, wn = (wid & 1) * 64;
  const int bm = blockIdx.x, bn = blockIdx.y;

  const int r0 = t >> 2, c8 = (t & 3) * 8;
  const unsigned short* gA0 = A + (size_t)(bm * 128 + r0) * EMBED + c8;
  const unsigned short* gB0 = B + (size_t)(bn * 128 + r0) * EMBED + c8;
  unsigned short* lA0 = sA + wid * 512;
  unsigned short* lA1 = sA + 2048 + wid * 512;
  unsigned short* lB0 = sB + wid * 512;
  unsigned short* lB1 = sB + 2048 + wid * 512;

  f32x4 acc[4][4];
#pragma unroll
  for (int i = 0; i < 4; ++i)
#pragma unroll
    for (int j = 0; j < 4; ++j) acc[i][j] = (f32x4){0.f, 0.f, 0.f, 0.f};

  for (int k0 = 0; k0 < EMBED; k0 += 32) {
    __syncthreads();
    gload16(gA0 + k0, lA0);
    gload16(gA0 + 64 * EMBED + k0, lA1);
    gload16(gB0 + k0, lB0);
    gload16(gB0 + 64 * EMBED + k0, lB1);
    __syncthreads();
    bf16x8 af[4], bfr[4];
#pragma unroll
    for (int mi = 0; mi < 4; ++mi)
      af[mi] = *(const bf16x8*)(sA + (wm + mi * 16 + l15) * 32 + quad * 8);
#pragma unroll
    for (int ni = 0; ni < 4; ++ni)
      bfr[ni] = *(const bf16x8*)(sB + (wn + ni * 16 + l15) * 32 + quad * 8);
#pragma unroll
    for (int mi = 0; mi < 4; ++mi)
#pragma unroll
      for (int ni = 0; ni < 4; ++ni)
        acc[mi][ni] = __builtin_amdgcn_mfma_f32_16x16x32_bf16(
            af[mi], bfr[ni], acc[mi][ni], 0, 0, 0);
  }

  const int hh = (bn * 128 + wn) >> 6;   // 0..47 enumerates (part, head)
  unsigned short* buf = qkvh + (size_t)hh * (MTOT * HDIM);
  float bv[4];
#pragma unroll
  for (int ni = 0; ni < 4; ++ni) bv[ni] = bias[bn * 128 + wn + ni * 16 + l15];
#pragma unroll
  for (int mi = 0; mi < 4; ++mi) {
#pragma unroll
    for (int reg = 0; reg < 4; ++reg) {
      int row = bm * 128 + wm + mi * 16 + quad * 4 + reg;
      int i = inv[row];
#pragma unroll
      for (int ni = 0; ni < 4; ++ni) {
        buf[(size_t)i * HDIM + ni * 16 + l15] = f2b(acc[mi][ni][reg] + bv[ni]);
      }
    }
  }
}

// ---------------------------------------------------------------------------
// rope_qk: in-place RoPE on qkvh head-slots 0..31 (Q scaled by 0.125).
// Window order == rope table order -> fully coalesced streaming.
// Each thread owns both rotation partners (d-chunks dc and dc+4).
// ---------------------------------------------------------------------------
__global__ __launch_bounds__(256) void rope_qk(
    const float* __restrict__ rope_cos, const float* __restrict__ rope_sin,
    unsigned short* __restrict__ qkvh)
{
  int g = blockIdx.x * 256 + threadIdx.x;  // 32*16384*4 = 2,097,152 threads
  int dc = g & 3;
  int i  = (g >> 2) & (MTOT - 1);
  int hh = g >> 16;
  unsigned short* p = qkvh + ((size_t)hh * MTOT + i) * HDIM;
  bf16x8 lo = *(const bf16x8*)(p + dc * 8);        // d in [dc*8, dc*8+8)
  bf16x8 hi = *(const bf16x8*)(p + 32 + dc * 8);   // partner d+32
  const float* cp = rope_cos + (size_t)i * HDIM + dc * 8;
  const float* sp = rope_sin + (size_t)i * HDIM + dc * 8;
  float cl[8], ch[8], sl[8], sh[8];
  *(float4*)(cl)     = *(const float4*)(cp);
  *(float4*)(cl + 4) = *(const float4*)(cp + 4);
  *(float4*)(ch)     = *(const float4*)(cp + 32);
  *(float4*)(ch + 4) = *(const float4*)(cp + 36);
  *(float4*)(sl)     = *(const float4*)(sp);
  *(float4*)(sl + 4) = *(const float4*)(sp + 4);
  *(float4*)(sh)     = *(const float4*)(sp + 32);
  *(float4*)(sh + 4) = *(const float4*)(sp + 36);
  const float sc = (hh < 16) ? 0.125f : 1.0f;
  bf16x8 olo, ohi;
#pragma unroll
  for (int j = 0; j < 8; ++j) {
    float a = b2f((unsigned short)lo[j]);
    float b = b2f((unsigned short)hi[j]);
    olo[j] = (short)f2b((a * cl[j] - b * sl[j]) * sc);
    ohi[j] = (short)f2b((b * ch[j] + a * sh[j]) * sc);
  }
  *(bf16x8*)(p + dc * 8) = olo;
  *(bf16x8*)(p + 32 + dc * 8) = ohi;
}

// ---------------------------------------------------------------------------
// cast_w: proj_w fp32 -> bf16, into the (now dead) Q region of qkvh.
// Runs after attn, before gemm_proj.
// ---------------------------------------------------------------------------
__global__ __launch_bounds__(256) void cast_w(
    const float* __restrict__ w, unsigned short* __restrict__ wb)
{
  int g = blockIdx.x * 256 + threadIdx.x;  // 1024*1024/8 = 131072 threads
  size_t e = (size_t)g * 8;
  float4 a = *(const float4*)(w + e);
  float4 b = *(const float4*)(w + e + 4);
  ushort4 u0, u1;
  u0.x = f2b(a.x); u0.y = f2b(a.y); u0.z = f2b(a.z); u0.w = f2b(a.w);
  u1.x = f2b(b.x); u1.y = f2b(b.y); u1.z = f2b(b.z); u1.w = f2b(b.w);
  *(ushort4*)(wb + e) = u0;
  *(ushort4*)(wb + e + 4) = u1;
}

// ---------------------------------------------------------------------------
// Attention: one block per (window, head). Q/K/V pre-gathered, pre-RoPE'd,
// head-major -> staging is a pure copy. Output scattered via kvi.
// ---------------------------------------------------------------------------
__global__ __launch_bounds__(256, 4) void attn(
    const unsigned short* __restrict__ qkvh,
    const int* __restrict__ kvi,
    unsigned short* __restrict__ ori)
{
  __shared__ __align__(16) unsigned short sK[128 * 64];   // [key][d] swizzled
  __shared__ __align__(16) unsigned short sV[64 * 128];   // [d][key] swizzled
  __shared__ __align__(16) unsigned short sP[4][16 * 40]; // per-wave P chunk

  const int t = threadIdx.x;
  const int lane = t & 63, wid = t >> 6;
  const int l15 = lane & 15, quad = lane >> 4;
  const int wwin = blockIdx.x >> 4;
  const int h = blockIdx.x & 15;

  const unsigned short* Qh = qkvh + (size_t)h * (MTOT * HDIM);
  const unsigned short* Kh = qkvh + (size_t)(16 + h) * (MTOT * HDIM);
  const unsigned short* Vh = qkvh + (size_t)(32 + h) * (MTOT * HDIM);

  f32x4 accO[4][4];
  float mrow[4][4], lrow[4][4];
#pragma unroll
  for (int qt = 0; qt < 4; ++qt) {
#pragma unroll
    for (int nt = 0; nt < 4; ++nt) accO[qt][nt] = (f32x4){0.f, 0.f, 0.f, 0.f};
#pragma unroll
    for (int reg = 0; reg < 4; ++reg) { mrow[qt][reg] = -1e30f; lrow[qt][reg] = 0.f; }
  }

  bf16x8 qa[4][2];
#pragma unroll
  for (int qt = 0; qt < 4; ++qt) {
    int i = wwin * 256 + wid * 64 + qt * 16 + l15;
    const unsigned short* qp = Qh + (size_t)i * HDIM;
    qa[qt][0] = *(const bf16x8*)(qp + quad * 8);
    qa[qt][1] = *(const bf16x8*)(qp + 32 + quad * 8);
  }

  for (int half = 0; half < 2; ++half) {
    __syncthreads();
    {
      int key = t >> 1, hx = t & 1;
      int i = wwin * 256 + half * 128 + key;
      const unsigned short* kp = Kh + (size_t)i * HDIM + hx * 32;
#pragma unroll
      for (int cc = 0; cc < 4; ++cc) {
        int c = hx * 4 + cc;
        uint4 kv = *(const uint4*)(kp + cc * 8);
        *(uint4*)(sK + key * 64 + ((c ^ (key & 7)) * 8)) = kv;
      }
      const unsigned short* vp = Vh + (size_t)i * HDIM + hx * 32;
      int kc3 = key >> 3, k7 = key & 7;
#pragma unroll
      for (int c = 0; c < 4; ++c) {
        bf16x8 va = *(const bf16x8*)(vp + c * 8);
#pragma unroll
        for (int j = 0; j < 8; ++j) {
          int d = hx * 32 + c * 8 + j;
          sV[d * 128 + ((kc3 ^ (d & 7)) * 8) + k7] = (unsigned short)va[j];
        }
      }
    }
    __syncthreads();

#pragma unroll
    for (int qt = 0; qt < 4; ++qt) {
      f32x4 accS[8];
#pragma unroll
      for (int nt = 0; nt < 8; ++nt) accS[nt] = (f32x4){0.f, 0.f, 0.f, 0.f};
#pragma unroll
      for (int ks = 0; ks < 2; ++ks) {
#pragma unroll
        for (int nt = 0; nt < 8; ++nt) {
          int key = nt * 16 + l15;
          bf16x8 bk = *(const bf16x8*)(
              sK + key * 64 + (((ks * 4 + quad) ^ (key & 7)) * 8));
          accS[nt] = __builtin_amdgcn_mfma_f32_16x16x32_bf16(
              qa[qt][ks], bk, accS[nt], 0, 0, 0);
        }
      }
#pragma unroll
      for (int reg = 0; reg < 4; ++reg) {
        float mx = accS[0][reg];
#pragma unroll
        for (int nt = 1; nt < 8; ++nt) mx = fmaxf(mx, accS[nt][reg]);
#pragma unroll
        for (int off = 1; off < 16; off <<= 1)
          mx = fmaxf(mx, __shfl_xor(mx, off, 64));
        float mold = mrow[qt][reg];
        float mnew = fmaxf(mold, mx);
        float alpha = __expf(mold - mnew);
        mrow[qt][reg] = mnew;
        float ls = 0.f;
#pragma unroll
        for (int nt = 0; nt < 8; ++nt) {
          float p = __expf(accS[nt][reg] - mnew);
          accS[nt][reg] = p;
          ls += p;
        }
#pragma unroll
        for (int off = 1; off < 16; off <<= 1) ls += __shfl_xor(ls, off, 64);
        lrow[qt][reg] = lrow[qt][reg] * alpha + ls;
#pragma unroll
        for (int nt = 0; nt < 4; ++nt) accO[qt][nt][reg] *= alpha;
      }
#pragma unroll
      for (int kc = 0; kc < 4; ++kc) {
#pragma unroll
        for (int nt2 = 0; nt2 < 2; ++nt2) {
#pragma unroll
          for (int reg = 0; reg < 4; ++reg) {
            sP[wid][(quad * 4 + reg) * 40 + nt2 * 16 + l15] =
                f2b(accS[kc * 2 + nt2][reg]);
          }
        }
        bf16x8 pa = *(const bf16x8*)(&sP[wid][l15 * 40 + quad * 8]);
#pragma unroll
        for (int nt = 0; nt < 4; ++nt) {
          int d = nt * 16 + l15;
          bf16x8 bv = *(const bf16x8*)(
              sV + d * 128 + (((kc * 4 + quad) ^ (d & 7)) * 8));
          accO[qt][nt] = __builtin_amdgcn_mfma_f32_16x16x32_bf16(
              pa, bv, accO[qt][nt], 0, 0, 0);
        }
      }
    }
  }

#pragma unroll
  for (int qt = 0; qt < 4; ++qt) {
#pragma unroll
    for (int reg = 0; reg < 4; ++reg) {
      int i = wwin * 256 + wid * 64 + qt * 16 + quad * 4 + reg;
      int orow = kvi[i];
      float inv = 1.0f / lrow[qt][reg];
      unsigned short* op = ori + (size_t)orow * EMBED + h * HDIM;
#pragma unroll
      for (int nt = 0; nt < 4; ++nt) {
        op[nt * 16 + l15] = f2b(accO[qt][nt][reg] * inv);
      }
    }
  }
}

// ---------------------------------------------------------------------------
// GEMM2 (m97 both sides): out = ori[:L] @ wpb^T + proj_b, out fp32.
// ---------------------------------------------------------------------------
__global__ __launch_bounds__(256) void gemm_proj(
    const unsigned short* __restrict__ A, const unsigned short* __restrict__ B,
    const float* __restrict__ bias, float* __restrict__ out)
{
  __shared__ __align__(16) unsigned short sA[128 * 32];
  __shared__ __align__(16) unsigned short sB[128 * 32];
  const int t = threadIdx.x;
  const int lane = t & 63, wid = t >> 6;
  const int l15 = lane & 15, quad = lane >> 4;
  const int wm = (wid >> 1) * 64, wn = (wid & 1) * 64;
  const int bm = blockIdx.x, bn = blockIdx.y;

  const int r0 = t >> 2, c8 = (t & 3) * 8;
  const unsigned short* gA0 = A + (size_t)(bm * 128 + r0) * EMBED + c8;
  const unsigned short* gB0 = B + (size_t)(bn * 128 + r0) * EMBED + c8;
  unsigned short* lA0 = sA + wid * 512;
  unsigned short* lA1 = sA + 2048 + wid * 512;
  unsigned short* lB0 = sB + wid * 512;
  unsigned short* lB1 = sB + 2048 + wid * 512;

  f32x4 acc[4][4];
#pragma unroll
  for (int i = 0; i < 4; ++i)
#pragma unroll
    for (int j = 0; j < 4; ++j) acc[i][j] = (f32x4){0.f, 0.f, 0.f, 0.f};

  for (int k0 = 0; k0 < EMBED; k0 += 32) {
    __syncthreads();
    gload16(gA0 + k0, lA0);
    gload16(gA0 + 64 * EMBED + k0, lA1);
    gload16(gB0 + k0, lB0);
    gload16(gB0 + 64 * EMBED + k0, lB1);
    __syncthreads();
    bf16x8 af[4], bfr[4];
#pragma unroll
    for (int mi = 0; mi < 4; ++mi)
      af[mi] = *(const bf16x8*)(sA + (wm + mi * 16 + l15) * 32 + quad * 8);
#pragma unroll
    for (int ni = 0; ni < 4; ++ni)
      bfr[ni] = *(const bf16x8*)(sB + (wn + ni * 16 + l15) * 32 + quad * 8);
#pragma unroll
    for (int mi = 0; mi < 4; ++mi)
#pragma unroll
      for (int ni = 0; ni < 4; ++ni)
        acc[mi][ni] = __builtin_amdgcn_mfma_f32_16x16x32_bf16(
            af[mi], bfr[ni], acc[mi][ni], 0, 0, 0);
  }

#pragma unroll
  for (int ni = 0; ni < 4; ++ni) {
    int col = bn * 128 + wn + ni * 16 + l15;
    float bv = bias[col];
#pragma unroll
    for (int mi = 0; mi < 4; ++mi) {
#pragma unroll
      for (int reg = 0; reg < 4; ++reg) {
        int row = bm * 128 + wm + mi * 16 + quad * 4 + reg;
        if (row < LTOT) out[(size_t)row * EMBED + col] = acc[mi][ni][reg] + bv;
      }
    }
  }
}

// ---------------------------------------------------------------------------
extern "C" void kernel_launch(void* const* d_in, const int* in_sizes, int n_in,
                              void* d_out, int out_size, void* d_ws, size_t ws_size,
                              hipStream_t stream) {
  const float* x        = (const float*)d_in[0];
  const float* qkv_w    = (const float*)d_in[1];
  const float* qkv_b    = (const float*)d_in[2];
  const float* proj_w   = (const float*)d_in[3];
  const float* proj_b   = (const float*)d_in[4];
  const float* padding  = (const float*)d_in[5];
  const float* rope_cos = (const float*)d_in[6];
  const float* rope_sin = (const float*)d_in[7];
  const int*   kvi      = (const int*)d_in[8];

  // ws layout (134.2 MB, proven safe):
  //   [0, 100.66M):       qkvh — head-major, window-permuted [48][16384][64]
  //                       bf16; Q region doubles as wpb after attn.
  //   [100.66M, +33.55M): xb (cast+gemm_qkv) then ori (attn+gemm_proj)
  // d_out scratch (dead before gemm_proj's writes):
  //   head: wqb (6.3 MB);  tail: inv (64 KB int32) — both read only by
  //   gemm_qkv, which completes before gemm_proj (stream order).
  unsigned short* qkvh = (unsigned short*)d_ws;
  unsigned short* R    = (unsigned short*)((char*)d_ws +
                            (size_t)MTOT * THREE_EMBED * 2);
  unsigned short* xb  = R;
  unsigned short* ori = R;
  unsigned short* wqb = (unsigned short*)d_out;
  unsigned short* wpb = qkvh;  // Q region, dead after attn
  int* inv = (int*)((char*)d_out + (size_t)LTOT * EMBED * 4 - (size_t)MTOT * 4);
  float* out = (float*)d_out;

  cast_inputs<<<4096, 256, 0, stream>>>(x, padding, qkv_w, kvi, xb, wqb, inv);
  gemm_qkv<<<dim3(128, 24), 256, 0, stream>>>(xb, wqb, qkv_b, inv, qkvh);
  rope_qk<<<8192, 256, 0, stream>>>(rope_cos, rope_sin, qkvh);
  attn<<<dim3(64 * 16), 256, 0, stream>>>(qkvh, kvi, ori);
  cast_w<<<512, 256, 0, stream>>>(proj_w, wpb);
  gemm_proj<<<dim3(128, 8), 256, 0, stream>>>(ori, wpb, proj_b, out);
}